// Round 4
// baseline (213.168 us; speedup 1.0000x reference)
//
#include <hip/hip_runtime.h>
#include <hip/hip_bf16.h>

typedef __attribute__((ext_vector_type(8))) short short8;
typedef __attribute__((ext_vector_type(4))) float f32x4;

#define NROWS 8192
#define DIM   1024
#define NCH   256
#define CHROW 32        // rows per chunk
#define XROW  1088      // xb row stride (1024 + aug col + pad to 64-mult)
#define MROW  1152      // Mt row stride / dims (9 * 128)
#define KTG   1088      // tgemm K extent (cols 1025..1087 are zero)

#define BM 128
#define BN 128
#define BK 64

__device__ __forceinline__ float bf2f(unsigned short u) {
    union { unsigned int i; float f; } v; v.i = ((unsigned int)u) << 16; return v.f;
}
__device__ __forceinline__ unsigned short f2bf(float f) {
    union { float f; unsigned int i; } v; v.f = f;
    unsigned int r = v.i + 0x7fffu + ((v.i >> 16) & 1u);
    return (unsigned short)(r >> 16);
}
__device__ __forceinline__ void gload_lds16(const unsigned short* g, unsigned short* l) {
    __builtin_amdgcn_global_load_lds(
        (const __attribute__((address_space(1))) void*)g,
        (__attribute__((address_space(3))) void*)l, 16, 0, 0);
}

// ---------------------------------------------------------------- prep
// blocks [0,512): 64x64 transpose tiles fp32->bf16  (Wq->WqTb, Wk->WkTb)
// blocks [512,528): augmentation rows 1024..1151 (row1024=bias, rest 0)
// blocks [528,784): per-chunk column sums of x -> csums fp32
__global__ __launch_bounds__(256) void prep(
    const float* __restrict__ Wq, const float* __restrict__ bq,
    const float* __restrict__ Wk, const float* __restrict__ bk,
    const float* __restrict__ x,
    unsigned short* __restrict__ WqTb, unsigned short* __restrict__ WkTb,
    float* __restrict__ csums)
{
    __shared__ float sTf[64 * 65];
    const int bid = blockIdx.x, t = threadIdx.x;
    if (bid < 512) {
        const int mat = bid >> 8, t16 = bid & 255;
        const int h0 = (t16 >> 4) * 64, a0 = (t16 & 15) * 64;
        const float* src = mat ? Wk : Wq;
        unsigned short* dst = mat ? WkTb : WqTb;
        #pragma unroll
        for (int i = 0; i < 4; ++i) {
            int g = i * 256 + t;                 // 1024 float4 groups
            int row = g >> 4, c4 = (g & 15) * 4;
            float4 v = *(const float4*)(src + (size_t)(h0 + row) * DIM + a0 + c4);
            sTf[row * 65 + c4 + 0] = v.x; sTf[row * 65 + c4 + 1] = v.y;
            sTf[row * 65 + c4 + 2] = v.z; sTf[row * 65 + c4 + 3] = v.w;
        }
        __syncthreads();
        #pragma unroll
        for (int i = 0; i < 4; ++i) {
            int g = i * 256 + t;
            int arow = g >> 4, h4 = (g & 15) * 4;
            ushort4 o;
            o.x = f2bf(sTf[(h4 + 0) * 65 + arow]);
            o.y = f2bf(sTf[(h4 + 1) * 65 + arow]);
            o.z = f2bf(sTf[(h4 + 2) * 65 + arow]);
            o.w = f2bf(sTf[(h4 + 3) * 65 + arow]);
            *(ushort4*)(dst + (size_t)(a0 + arow) * DIM + h0 + h4) = o;
        }
    } else if (bid < 528) {
        const int idx = bid - 512, mat = idx >> 3, seg = idx & 7;
        unsigned short* dst = mat ? WkTb : WqTb;
        const float* bias   = mat ? bk : bq;
        const int r0 = 1024 + seg * 16;
        #pragma unroll
        for (int i = 0; i < 16; ++i) {
            int g = i * 256 + t;                 // 4096 ushort4 groups
            int row = r0 + (g >> 8), c4 = (g & 255) * 4;
            ushort4 o;
            if (row == 1024) {
                o.x = f2bf(bias[c4 + 0]); o.y = f2bf(bias[c4 + 1]);
                o.z = f2bf(bias[c4 + 2]); o.w = f2bf(bias[c4 + 3]);
            } else { o.x = o.y = o.z = o.w = 0; }
            *(ushort4*)(dst + (size_t)row * DIM + c4) = o;
        }
    } else {
        const int ch = bid - 528, c4 = t * 4;
        float s0 = 0.f, s1 = 0.f, s2 = 0.f, s3 = 0.f;
        #pragma unroll 4
        for (int r = 0; r < CHROW; ++r) {
            float4 v = *(const float4*)(x + (size_t)(ch * CHROW + r) * DIM + c4);
            s0 += v.x; s1 += v.y; s2 += v.z; s3 += v.w;
        }
        f32x4 o; o[0] = s0; o[1] = s1; o[2] = s2; o[3] = s3;
        *(f32x4*)&csums[(size_t)ch * DIM + c4] = o;
    }
}

// ---------------------------------------------------------------- cscan
// in-place exclusive scan over chunks per column
__global__ __launch_bounds__(256) void cscan(float* __restrict__ csums)
{
    const int col = blockIdx.x * 256 + threadIdx.x;
    float run = 0.f;
    #pragma unroll 8
    for (int ch = 0; ch < NCH; ++ch) {
        float v = csums[(size_t)ch * DIM + col];
        csums[(size_t)ch * DIM + col] = run;
        run += v;
    }
}

// ---------------------------------------------------------------- scan_write
// writes xb (bf16, aug col 1024 = 1.0, 1025..1087 = 0) and P (bf16 exclusive prefix)
__global__ __launch_bounds__(256) void scan_write(
    const float* __restrict__ x, const float* __restrict__ csums,
    unsigned short* __restrict__ xb, unsigned short* __restrict__ P)
{
    const int ch = blockIdx.x, t = threadIdx.x, c4 = t * 4;
    f32x4 run = *(const f32x4*)&csums[(size_t)ch * DIM + c4];
    for (int r = 0; r < CHROW; ++r) {
        size_t row = (size_t)ch * CHROW + r;
        float4 xv = *(const float4*)(x + row * DIM + c4);
        ushort4 pb; pb.x = f2bf(run[0]); pb.y = f2bf(run[1]);
        pb.z = f2bf(run[2]); pb.w = f2bf(run[3]);
        *(ushort4*)(P + row * DIM + c4) = pb;
        ushort4 xo; xo.x = f2bf(xv.x); xo.y = f2bf(xv.y);
        xo.z = f2bf(xv.z); xo.w = f2bf(xv.w);
        *(ushort4*)(xb + row * XROW + c4) = xo;
        run[0] += xv.x; run[1] += xv.y; run[2] += xv.z; run[3] += xv.w;
    }
    {
        int r = t >> 3, cg = (t & 7) * 8;
        size_t row = (size_t)ch * CHROW + r;
        ushort4 z0, z1; z1.x = z1.y = z1.z = z1.w = 0;
        z0 = z1;
        if (cg == 0) z0.x = 0x3F80;   // col 1024 = 1.0
        *(ushort4*)(xb + row * XROW + 1024 + cg) = z0;
        *(ushort4*)(xb + row * XROW + 1024 + cg + 4) = z1;
    }
}

// ---------------------------------------------------------------- mgemm
// Mt[b][a] = sum_h WkT[b][h] * WqT[a][h]   (1152 x 1152, K=1024), bf16 out
__global__ __launch_bounds__(256) void mgemm(
    const unsigned short* __restrict__ A,   // WkTb 1152 x 1024
    const unsigned short* __restrict__ B,   // WqTb 1152 x 1024
    unsigned short* __restrict__ Mt)        // 1152 x 1152
{
    __shared__ unsigned short sA[BM * BK];
    __shared__ unsigned short sB[BN * BK];
    const int tid = threadIdx.x, wave = tid >> 6, lane = tid & 63;
    const int quad = lane >> 4, l16 = lane & 15;
    const int m0 = blockIdx.x * BM, n0 = blockIdx.y * BN;
    const int wm = (wave >> 1) * 64, wn = (wave & 1) * 64;
    const int rsel = lane >> 3, csel = (lane & 7) * 8;

    f32x4 acc[4][4];
    #pragma unroll
    for (int i = 0; i < 4; ++i)
        #pragma unroll
        for (int j = 0; j < 4; ++j) acc[i][j] = (f32x4)0.0f;

    for (int k0 = 0; k0 < DIM; k0 += BK) {
        __syncthreads();
        #pragma unroll
        for (int j = 0; j < 4; ++j) {
            const int row = wave * 32 + j * 8;
            gload_lds16(A + (size_t)(m0 + row + rsel) * DIM + k0 + csel, &sA[row * BK]);
            gload_lds16(B + (size_t)(n0 + row + rsel) * DIM + k0 + csel, &sB[row * BK]);
        }
        __syncthreads();
        #pragma unroll
        for (int ks = 0; ks < 2; ++ks) {
            const int kc = ks * 32 + quad * 8;
            short8 af[4], bfr[4];
            #pragma unroll
            for (int tt = 0; tt < 4; ++tt)
                af[tt] = *(const short8*)&sA[(wm + tt * 16 + l16) * BK + kc];
            #pragma unroll
            for (int tt = 0; tt < 4; ++tt)
                bfr[tt] = *(const short8*)&sB[(wn + tt * 16 + l16) * BK + kc];
            #pragma unroll
            for (int mt = 0; mt < 4; ++mt)
                #pragma unroll
                for (int nt = 0; nt < 4; ++nt)
                    acc[mt][nt] = __builtin_amdgcn_mfma_f32_16x16x32_bf16(
                        af[mt], bfr[nt], acc[mt][nt], 0, 0, 0);
        }
    }
    #pragma unroll
    for (int nt = 0; nt < 4; ++nt) {
        int n = n0 + wn + nt * 16 + l16;
        #pragma unroll
        for (int mt = 0; mt < 4; ++mt)
            #pragma unroll
            for (int r = 0; r < 4; ++r) {
                int m = m0 + wm + mt * 16 + quad * 4 + r;
                Mt[(size_t)m * MROW + n] = f2bf(acc[mt][nt][r]);
            }
    }
}

// ---------------------------------------------------------------- tgemm
// T[i][n] = sum_k xb[i][k] * Mt[n][k]  (M=8192, N=1152, K=1088)
// store bf16 T for n<1024; n==1024 -> g2[i] fp32 (the q·bk column)
__global__ __launch_bounds__(256) void tgemm(
    const unsigned short* __restrict__ A,   // xb 8192 x XROW
    const unsigned short* __restrict__ B,   // Mt 1152 x MROW
    unsigned short* __restrict__ T,         // 8192 x 1024
    float* __restrict__ g2)                 // 8192
{
    __shared__ unsigned short sA[BM * BK];
    __shared__ unsigned short sB[BN * BK];
    const int tid = threadIdx.x, wave = tid >> 6, lane = tid & 63;
    const int quad = lane >> 4, l16 = lane & 15;
    const int m0 = blockIdx.x * BM, n0 = blockIdx.y * BN;
    const int wm = (wave >> 1) * 64, wn = (wave & 1) * 64;
    const int rsel = lane >> 3, csel = (lane & 7) * 8;

    f32x4 acc[4][4];
    #pragma unroll
    for (int i = 0; i < 4; ++i)
        #pragma unroll
        for (int j = 0; j < 4; ++j) acc[i][j] = (f32x4)0.0f;

    for (int k0 = 0; k0 < KTG; k0 += BK) {
        __syncthreads();
        #pragma unroll
        for (int j = 0; j < 4; ++j) {
            const int row = wave * 32 + j * 8;
            gload_lds16(A + (size_t)(m0 + row + rsel) * XROW + k0 + csel, &sA[row * BK]);
            gload_lds16(B + (size_t)(n0 + row + rsel) * MROW + k0 + csel, &sB[row * BK]);
        }
        __syncthreads();
        #pragma unroll
        for (int ks = 0; ks < 2; ++ks) {
            const int kc = ks * 32 + quad * 8;
            short8 af[4], bfr[4];
            #pragma unroll
            for (int tt = 0; tt < 4; ++tt)
                af[tt] = *(const short8*)&sA[(wm + tt * 16 + l16) * BK + kc];
            #pragma unroll
            for (int tt = 0; tt < 4; ++tt)
                bfr[tt] = *(const short8*)&sB[(wn + tt * 16 + l16) * BK + kc];
            #pragma unroll
            for (int mt = 0; mt < 4; ++mt)
                #pragma unroll
                for (int nt = 0; nt < 4; ++nt)
                    acc[mt][nt] = __builtin_amdgcn_mfma_f32_16x16x32_bf16(
                        af[mt], bfr[nt], acc[mt][nt], 0, 0, 0);
        }
    }
    #pragma unroll
    for (int nt = 0; nt < 4; ++nt) {
        int n = n0 + wn + nt * 16 + l16;
        #pragma unroll
        for (int mt = 0; mt < 4; ++mt)
            #pragma unroll
            for (int r = 0; r < 4; ++r) {
                int m = m0 + wm + mt * 16 + quad * 4 + r;
                float v = acc[mt][nt][r];
                if (n < 1024)       T[(size_t)m * DIM + n] = f2bf(v);
                else if (n == 1024) g2[m] = v;
            }
    }
}

// ---------------------------------------------------------------- finalize
// out[i][:] = sum_c T[i][c]*P[i][c] + i*g2[i]
__global__ __launch_bounds__(256) void finalize(
    const unsigned short* __restrict__ T, const unsigned short* __restrict__ P,
    const float* __restrict__ g2, float* __restrict__ out)
{
    __shared__ float sP[CHROW * 256];
    __shared__ float rowval[CHROW];
    const int t = threadIdx.x, ch = blockIdx.x, c4 = t * 4;
    float part[CHROW];
    #pragma unroll 4
    for (int r = 0; r < CHROW; ++r) {
        size_t row = (size_t)ch * CHROW + r;
        ushort4 tv = *(const ushort4*)&T[row * DIM + c4];
        ushort4 pv = *(const ushort4*)&P[row * DIM + c4];
        part[r] = bf2f(tv.x) * bf2f(pv.x) + bf2f(tv.y) * bf2f(pv.y)
                + bf2f(tv.z) * bf2f(pv.z) + bf2f(tv.w) * bf2f(pv.w);
    }
    #pragma unroll
    for (int r = 0; r < CHROW; ++r) sP[r * 256 + t] = part[r];
    __syncthreads();
    const int wave = t >> 6, lane = t & 63;
    #pragma unroll
    for (int r8 = 0; r8 < 8; ++r8) {
        int r = wave * 8 + r8;
        float v = sP[r * 256 + lane]       + sP[r * 256 + 64 + lane]
                + sP[r * 256 + 128 + lane] + sP[r * 256 + 192 + lane];
        #pragma unroll
        for (int s = 32; s >= 1; s >>= 1) v += __shfl_xor(v, s, 64);
        if (lane == 0) rowval[r] = v;
    }
    __syncthreads();
    #pragma unroll
    for (int r = 0; r < CHROW; ++r) {
        size_t row = (size_t)ch * CHROW + r;
        float rv = rowval[r] + (float)row * g2[row];
        f32x4 o = (f32x4)rv;
        *(f32x4*)&out[row * DIM + c4] = o;
    }
}

// ---------------------------------------------------------------- launch
extern "C" void kernel_launch(void* const* d_in, const int* in_sizes, int n_in,
                              void* d_out, int out_size, void* d_ws, size_t ws_size,
                              hipStream_t stream)
{
    const float* x  = (const float*)d_in[0];
    const float* Wk = (const float*)d_in[1];
    const float* bk = (const float*)d_in[2];
    const float* Wq = (const float*)d_in[5];
    const float* bq = (const float*)d_in[6];
    float* out = (float*)d_out;

    // Non-overlapping layout (byte offsets; previous round overlapped WqTb/WkTb):
    //   xb    [0, 17 MiB)              8192*1088*2 = 17,825,792
    //   P     [17 MiB, 33 MiB)         16 MiB
    //   T     [33 MiB, 49 MiB)         16 MiB
    //   WqTb  [49.0 MiB, 51.25 MiB)    2.25 MiB
    //   WkTb  [51.5 MiB, 53.75 MiB)    2.25 MiB
    //   Mt    [54.0 MiB, 56.6 MiB)     1152*1152*2 = 2,654,208
    //   csums [57 MiB, 58 MiB)         1 MiB
    //   g2    [58.5 MiB, +32 KiB)
    char* ws = (char*)d_ws;
    const size_t MiB = 1048576;
    unsigned short* xb   = (unsigned short*)(ws);
    unsigned short* P    = (unsigned short*)(ws + 17 * MiB);
    unsigned short* T    = (unsigned short*)(ws + 33 * MiB);
    unsigned short* WqTb = (unsigned short*)(ws + 49 * MiB);
    unsigned short* WkTb = (unsigned short*)(ws + 49 * MiB + 2621440);
    unsigned short* Mt   = (unsigned short*)(ws + 49 * MiB + 5242880);
    float* csums         = (float*)(ws + 57 * MiB);
    float* g2            = (float*)(ws + 58 * MiB + 524288);

    prep<<<784, 256, 0, stream>>>(Wq, bq, Wk, bk, x, WqTb, WkTb, csums);
    cscan<<<4, 256, 0, stream>>>(csums);
    scan_write<<<NCH, 256, 0, stream>>>(x, csums, xb, P);
    mgemm<<<dim3(9, 9), 256, 0, stream>>>(WkTb, WqTb, Mt);
    tgemm<<<dim3(64, 9), 256, 0, stream>>>(xb, Mt, T, g2);
    finalize<<<NCH, 256, 0, stream>>>(T, P, g2, out);
}

// Round 5
// 194.820 us; speedup vs baseline: 1.0942x; 1.0942x over previous
//
#include <hip/hip_runtime.h>
#include <hip/hip_bf16.h>

typedef __attribute__((ext_vector_type(8))) short short8;
typedef __attribute__((ext_vector_type(4))) float f32x4;

#define NROWS 8192
#define DIM   1024
#define NCH   256
#define CHROW 32        // rows per chunk
#define XROW  1088      // xb row stride (1024 + aug col 1024 + zero pad)
#define MROW  1152      // Mt row stride / dims
#define KTG   1088      // tgemm K extent

#define BM 128
#define BN 128
#define BK 64

__device__ __forceinline__ float bf2f(unsigned short u) {
    union { unsigned int i; float f; } v; v.i = ((unsigned int)u) << 16; return v.f;
}
__device__ __forceinline__ unsigned short f2bf(float f) {
    union { float f; unsigned int i; } v; v.f = f;
    unsigned int r = v.i + 0x7fffu + ((v.i >> 16) & 1u);
    return (unsigned short)(r >> 16);
}
__device__ __forceinline__ void gload_lds16(const unsigned short* g, unsigned short* l) {
    __builtin_amdgcn_global_load_lds(
        (const __attribute__((address_space(1))) void*)g,
        (__attribute__((address_space(3))) void*)l, 16, 0, 0);
}

// ---------------------------------------------------------------- K1: prep
// [0,512)     : 64x64 transpose tiles fp32->bf16 (Wq->WqTb, Wk->WkTb)
// [512,528)   : augmentation rows 1024..1151 (row 1024 = bias, rest 0)
// [528,1040)  : per-chunk column sums of x (512 blocks: chunk x col-half)
// [1040,1056) : zero rsum(8192 f) + g2(8192 f) contiguous
__global__ __launch_bounds__(256) void prep(
    const float* __restrict__ Wq, const float* __restrict__ bq,
    const float* __restrict__ Wk, const float* __restrict__ bk,
    const float* __restrict__ x,
    unsigned short* __restrict__ WqTb, unsigned short* __restrict__ WkTb,
    float* __restrict__ csums, float* __restrict__ rsum)
{
    __shared__ float sTf[64 * 65];
    const int bid = blockIdx.x, t = threadIdx.x;
    if (bid < 512) {
        const int mat = bid >> 8, t16 = bid & 255;
        const int h0 = (t16 >> 4) * 64, a0 = (t16 & 15) * 64;
        const float* src = mat ? Wk : Wq;
        unsigned short* dst = mat ? WkTb : WqTb;
        #pragma unroll
        for (int i = 0; i < 4; ++i) {
            int g = i * 256 + t;
            int row = g >> 4, c4 = (g & 15) * 4;
            float4 v = *(const float4*)(src + (size_t)(h0 + row) * DIM + a0 + c4);
            sTf[row * 65 + c4 + 0] = v.x; sTf[row * 65 + c4 + 1] = v.y;
            sTf[row * 65 + c4 + 2] = v.z; sTf[row * 65 + c4 + 3] = v.w;
        }
        __syncthreads();
        #pragma unroll
        for (int i = 0; i < 4; ++i) {
            int g = i * 256 + t;
            int arow = g >> 4, h4 = (g & 15) * 4;
            ushort4 o;
            o.x = f2bf(sTf[(h4 + 0) * 65 + arow]);
            o.y = f2bf(sTf[(h4 + 1) * 65 + arow]);
            o.z = f2bf(sTf[(h4 + 2) * 65 + arow]);
            o.w = f2bf(sTf[(h4 + 3) * 65 + arow]);
            *(ushort4*)(dst + (size_t)(a0 + arow) * DIM + h0 + h4) = o;
        }
    } else if (bid < 528) {
        const int idx = bid - 512, mat = idx >> 3, seg = idx & 7;
        unsigned short* dst = mat ? WkTb : WqTb;
        const float* bias   = mat ? bk : bq;
        const int r0 = 1024 + seg * 16;
        #pragma unroll
        for (int i = 0; i < 16; ++i) {
            int g = i * 256 + t;
            int row = r0 + (g >> 8), c4 = (g & 255) * 4;
            ushort4 o;
            if (row == 1024) {
                o.x = f2bf(bias[c4 + 0]); o.y = f2bf(bias[c4 + 1]);
                o.z = f2bf(bias[c4 + 2]); o.w = f2bf(bias[c4 + 3]);
            } else { o.x = o.y = o.z = o.w = 0; }
            *(ushort4*)(dst + (size_t)row * DIM + c4) = o;
        }
    } else if (bid < 1040) {
        const int s = bid - 528, ch = s >> 1, half = s & 1;
        const int col = half * 512 + t * 2;
        float s0 = 0.f, s1 = 0.f;
        #pragma unroll
        for (int r = 0; r < CHROW; ++r) {
            float2 v = *(const float2*)(x + (size_t)(ch * CHROW + r) * DIM + col);
            s0 += v.x; s1 += v.y;
        }
        float2 o; o.x = s0; o.y = s1;
        *(float2*)&csums[(size_t)ch * DIM + col] = o;
    } else {
        const int idx = bid - 1040;             // 16 blocks zero 16384 floats
        f32x4 z = (f32x4)0.0f;
        *(f32x4*)&rsum[(idx * 256 + t) * 4] = z;
    }
}

// ---------------------------------------------------------------- K2: cscan
// in-place exclusive scan over chunks per column (deep unroll pipelines loads)
__global__ __launch_bounds__(256) void cscan(float* __restrict__ csums)
{
    const int col = blockIdx.x * 256 + threadIdx.x;
    float run = 0.f;
    #pragma unroll 32
    for (int ch = 0; ch < NCH; ++ch) {
        float v = csums[(size_t)ch * DIM + col];
        csums[(size_t)ch * DIM + col] = run;
        run += v;
    }
}

// ---------------------------------------------------------------- K3: scan_write + mgemm fused
// [0,512)   : scan_write — chunk x col-half; writes xb (bf16 + aug) and P (bf16)
// [512,593) : mgemm — Mt[b][a] = sum_h WkT[b][h]*WqT[a][h] (1152x1152, K=1024)
__global__ __launch_bounds__(256) void scan_mgemm(
    const float* __restrict__ x, const float* __restrict__ csums,
    unsigned short* __restrict__ xb, unsigned short* __restrict__ P,
    const unsigned short* __restrict__ WkTb, const unsigned short* __restrict__ WqTb,
    unsigned short* __restrict__ Mt)
{
    __shared__ unsigned short smem[2 * BM * BK];   // 32 KB
    const int t = threadIdx.x;
    if (blockIdx.x < 512) {
        const int s = blockIdx.x, ch = s >> 1, half = s & 1;
        const int col = half * 512 + t * 2;
        float2 run = *(const float2*)&csums[(size_t)ch * DIM + col];
        #pragma unroll
        for (int r = 0; r < CHROW; ++r) {
            size_t row = (size_t)ch * CHROW + r;
            float2 xv = *(const float2*)(x + row * DIM + col);
            ushort2 pb; pb.x = f2bf(run.x); pb.y = f2bf(run.y);
            *(ushort2*)(P + row * DIM + col) = pb;
            ushort2 xo; xo.x = f2bf(xv.x); xo.y = f2bf(xv.y);
            *(ushort2*)(xb + row * XROW + col) = xo;
            run.x += xv.x; run.y += xv.y;
        }
        if (half == 1) {      // aug cols 1024..1087 for this chunk
            int r = t >> 3, cg = (t & 7) * 8;
            size_t row = (size_t)ch * CHROW + r;
            ushort4 z0, z1; z1.x = z1.y = z1.z = z1.w = 0; z0 = z1;
            if (cg == 0) z0.x = 0x3F80;   // col 1024 = 1.0
            *(ushort4*)(xb + row * XROW + 1024 + cg) = z0;
            *(ushort4*)(xb + row * XROW + 1024 + cg + 4) = z1;
        }
    } else {
        unsigned short* sA = smem;
        unsigned short* sB = smem + BM * BK;
        const int s = blockIdx.x - 512;            // 0..80
        const int bx = s % 9, by = s / 9;
        const int wave = t >> 6, lane = t & 63;
        const int quad = lane >> 4, l16 = lane & 15;
        const int m0 = bx * BM, n0 = by * BN;
        const int wm = (wave >> 1) * 64, wn = (wave & 1) * 64;
        const int rsel = lane >> 3, csel = (lane & 7) * 8;

        f32x4 acc[4][4];
        #pragma unroll
        for (int i = 0; i < 4; ++i)
            #pragma unroll
            for (int j = 0; j < 4; ++j) acc[i][j] = (f32x4)0.0f;

        for (int k0 = 0; k0 < DIM; k0 += BK) {
            __syncthreads();
            #pragma unroll
            for (int j = 0; j < 4; ++j) {
                const int row = wave * 32 + j * 8;
                gload_lds16(WkTb + (size_t)(m0 + row + rsel) * DIM + k0 + csel, &sA[row * BK]);
                gload_lds16(WqTb + (size_t)(n0 + row + rsel) * DIM + k0 + csel, &sB[row * BK]);
            }
            __syncthreads();
            #pragma unroll
            for (int ks = 0; ks < 2; ++ks) {
                const int kc = ks * 32 + quad * 8;
                short8 af[4], bfr[4];
                #pragma unroll
                for (int tt = 0; tt < 4; ++tt)
                    af[tt] = *(const short8*)&sA[(wm + tt * 16 + l16) * BK + kc];
                #pragma unroll
                for (int tt = 0; tt < 4; ++tt)
                    bfr[tt] = *(const short8*)&sB[(wn + tt * 16 + l16) * BK + kc];
                #pragma unroll
                for (int mt = 0; mt < 4; ++mt)
                    #pragma unroll
                    for (int nt = 0; nt < 4; ++nt)
                        acc[mt][nt] = __builtin_amdgcn_mfma_f32_16x16x32_bf16(
                            af[mt], bfr[nt], acc[mt][nt], 0, 0, 0);
            }
        }
        #pragma unroll
        for (int nt = 0; nt < 4; ++nt) {
            int n = n0 + wn + nt * 16 + l16;
            #pragma unroll
            for (int mt = 0; mt < 4; ++mt)
                #pragma unroll
                for (int r = 0; r < 4; ++r) {
                    int m = m0 + wm + mt * 16 + quad * 4 + r;
                    Mt[(size_t)m * MROW + n] = f2bf(acc[mt][nt][r]);
                }
        }
    }
}

// ---------------------------------------------------------------- K4: tgemm + fused dot-reduction
// T[i][n] = sum_k xb[i][k]*Mt[n][k] (never materialized).
// y<8 : atomicAdd rsum[i] += sum_{n in patch} T[i][n]*P[i][n]
// y==8: atomicAdd g2[i] += T[i][1024] partial
// grid (64, 9, 2) — split-K (z=0: k<512, z=1: k>=512)
__global__ __launch_bounds__(256) void tgemm_red(
    const unsigned short* __restrict__ A,   // xb 8192 x XROW
    const unsigned short* __restrict__ B,   // Mt 1152 x MROW
    const unsigned short* __restrict__ P,   // 8192 x 1024
    float* __restrict__ rsum, float* __restrict__ g2)
{
    __shared__ unsigned short smem[2 * BM * BK];   // 32 KB; reused for P patch
    unsigned short* sA = smem;
    unsigned short* sB = smem + BM * BK;
    const int tid = threadIdx.x, wave = tid >> 6, lane = tid & 63;
    const int quad = lane >> 4, l16 = lane & 15;
    const int m0 = blockIdx.x * BM, n0 = blockIdx.y * BN;
    const int wm = (wave >> 1) * 64, wn = (wave & 1) * 64;
    const int rsel = lane >> 3, csel = (lane & 7) * 8;
    const int kbeg = blockIdx.z ? 512 : 0;
    const int kend = blockIdx.z ? KTG : 512;

    f32x4 acc[4][4];
    #pragma unroll
    for (int i = 0; i < 4; ++i)
        #pragma unroll
        for (int j = 0; j < 4; ++j) acc[i][j] = (f32x4)0.0f;

    for (int k0 = kbeg; k0 < kend; k0 += BK) {
        __syncthreads();
        #pragma unroll
        for (int j = 0; j < 4; ++j) {
            const int row = wave * 32 + j * 8;
            gload_lds16(A + (size_t)(m0 + row + rsel) * XROW + k0 + csel, &sA[row * BK]);
            gload_lds16(B + (size_t)(n0 + row + rsel) * MROW + k0 + csel, &sB[row * BK]);
        }
        __syncthreads();
        #pragma unroll
        for (int ks = 0; ks < 2; ++ks) {
            const int kc = ks * 32 + quad * 8;
            short8 af[4], bfr[4];
            #pragma unroll
            for (int tt = 0; tt < 4; ++tt)
                af[tt] = *(const short8*)&sA[(wm + tt * 16 + l16) * BK + kc];
            #pragma unroll
            for (int tt = 0; tt < 4; ++tt)
                bfr[tt] = *(const short8*)&sB[(wn + tt * 16 + l16) * BK + kc];
            #pragma unroll
            for (int mt = 0; mt < 4; ++mt)
                #pragma unroll
                for (int nt = 0; nt < 4; ++nt)
                    acc[mt][nt] = __builtin_amdgcn_mfma_f32_16x16x32_bf16(
                        af[mt], bfr[nt], acc[mt][nt], 0, 0, 0);
        }
    }

    if (blockIdx.y == 8) {
        // only col 1024 matters: wn==0, nt==0, l16==0 lanes hold it
        if (wn == 0 && l16 == 0) {
            #pragma unroll
            for (int mt = 0; mt < 4; ++mt)
                #pragma unroll
                for (int r = 0; r < 4; ++r)
                    atomicAdd(&g2[m0 + wm + mt * 16 + quad * 4 + r], acc[mt][0][r]);
        }
        return;
    }

    // stage P patch (128x128 bf16 = 32 KB) into smem, then per-row dot-reduce
    __syncthreads();
    #pragma unroll
    for (int j = 0; j < 8; ++j) {
        const int row = wave * 32 + j * 4;      // +quad per lane group
        gload_lds16(P + (size_t)(m0 + row + quad) * DIM + n0 + l16 * 8,
                    &smem[row * 128]);
    }
    __syncthreads();
    #pragma unroll
    for (int mt = 0; mt < 4; ++mt) {
        #pragma unroll
        for (int r = 0; r < 4; ++r) {
            const int lrow = wm + mt * 16 + quad * 4 + r;
            float v = 0.f;
            #pragma unroll
            for (int nt = 0; nt < 4; ++nt)
                v += acc[mt][nt][r] * bf2f(smem[lrow * 128 + wn + nt * 16 + l16]);
            v += __shfl_xor(v, 1, 64); v += __shfl_xor(v, 2, 64);
            v += __shfl_xor(v, 4, 64); v += __shfl_xor(v, 8, 64);
            if (l16 == 0) atomicAdd(&rsum[m0 + lrow], v);
        }
    }
}

// ---------------------------------------------------------------- K5: writeout
// out[i][:] = rsum[i] + i*g2[i]; one block per row
__global__ __launch_bounds__(256) void writeout(
    const float* __restrict__ rsum, const float* __restrict__ g2,
    float* __restrict__ out)
{
    const int row = blockIdx.x, t = threadIdx.x;
    const float v = rsum[row] + (float)row * g2[row];
    f32x4 o = (f32x4)v;
    *(f32x4*)&out[(size_t)row * DIM + t * 4] = o;
}

// ---------------------------------------------------------------- launch
extern "C" void kernel_launch(void* const* d_in, const int* in_sizes, int n_in,
                              void* d_out, int out_size, void* d_ws, size_t ws_size,
                              hipStream_t stream)
{
    const float* x  = (const float*)d_in[0];
    const float* Wk = (const float*)d_in[1];
    const float* bk = (const float*)d_in[2];
    const float* Wq = (const float*)d_in[5];
    const float* bq = (const float*)d_in[6];
    float* out = (float*)d_out;

    // layout (MiB offsets, non-overlapping):
    //   xb    @0     (17,825,792 B)   P @17 MiB (16 MiB)   Mt @33 MiB (2.6 MiB)
    //   WqTb  @36    (2.25 MiB)       WkTb @38.5 MiB (2.25 MiB)
    //   csums @41    (1 MiB)          rsum @42 MiB (32 KiB)  g2 @42 MiB+32 KiB
    char* ws = (char*)d_ws;
    const size_t MiB = 1048576;
    unsigned short* xb   = (unsigned short*)(ws);
    unsigned short* P    = (unsigned short*)(ws + 17 * MiB);
    unsigned short* Mt   = (unsigned short*)(ws + 33 * MiB);
    unsigned short* WqTb = (unsigned short*)(ws + 36 * MiB);
    unsigned short* WkTb = (unsigned short*)(ws + 38 * MiB + 524288);
    float* csums         = (float*)(ws + 41 * MiB);
    float* rsum          = (float*)(ws + 42 * MiB);
    float* g2            = (float*)(ws + 42 * MiB + 32768);

    prep<<<1056, 256, 0, stream>>>(Wq, bq, Wk, bk, x, WqTb, WkTb, csums, rsum);
    cscan<<<4, 256, 0, stream>>>(csums);
    scan_mgemm<<<593, 256, 0, stream>>>(x, csums, xb, P, WkTb, WqTb, Mt);
    tgemm_red<<<dim3(64, 9, 2), 256, 0, stream>>>(xb, Mt, P, rsum, g2);
    writeout<<<NROWS, 256, 0, stream>>>(rsum, g2, out);
}